// Round 5
// baseline (525.042 us; speedup 1.0000x reference)
//
#include <hip/hip_runtime.h>
#include <math.h>

// Problem shape (fixed by reference setup_inputs)
#define BATCH 32
#define SEQ   4096
#define HID   768
#define HV4   (HID / 4)                       // 192 float4 per row
#define CHUNKS 64                             // chunks per batch
#define ROWS_PER_BLOCK (SEQ / CHUNKS)         // 64
#define NWAVES 4
#define ROWS_PER_WAVE (ROWS_PER_BLOCK / NWAVES) // 16
#define RGROUP 2                              // rows per group (fits 64-VGPR budget)

// native clang vector type so __builtin_nontemporal_load works
typedef __attribute__((ext_vector_type(4))) float f4v;

__device__ __forceinline__ float dot4(f4v a, f4v b) {
  return a.x * b.x + a.y * b.y + a.z * b.z + a.w * b.w;
}

// Pass 1: one block per (chunk, batch). Each wave runs online softmax over its
// 16 rows in groups of 2. Rows are read ONCE (nontemporal streaming loads).
// __launch_bounds__(256,8): 64-VGPR cap -> 8 blocks/CU = 32 waves/CU, max
// occupancy to keep the HBM request stream dense.
__global__ __launch_bounds__(256, 8)
void attn_pass1(const float* __restrict__ hidden,
                const float* __restrict__ q,
                float* __restrict__ m_ws,
                float* __restrict__ l_ws,
                float* __restrict__ o_ws) {
  const int chunk = blockIdx.x;
  const int b     = blockIdx.y;
  const int tid   = threadIdx.x;
  const int wave  = tid >> 6;
  const int lane  = tid & 63;

  // Query fragment for this lane: h = 4*lane..4*lane+3, +256, +512
  const f4v* q4 = reinterpret_cast<const f4v*>(q);
  const f4v qa = q4[lane];
  const f4v qb = q4[lane + 64];
  const f4v qc = q4[lane + 128];

  float m = -INFINITY;
  float l = 0.0f;
  f4v oa = (f4v)0.0f;
  f4v ob = (f4v)0.0f;
  f4v oc = (f4v)0.0f;

  const int row0 = chunk * ROWS_PER_BLOCK + wave * ROWS_PER_WAVE;
  const f4v* base = reinterpret_cast<const f4v*>(hidden)
                  + ((size_t)b * SEQ + (size_t)row0) * HV4;

  for (int g = 0; g < ROWS_PER_WAVE; g += RGROUP) {
    f4v ra[RGROUP], rb[RGROUP], rc[RGROUP];
    #pragma unroll
    for (int r = 0; r < RGROUP; ++r) {
      const f4v* rp = base + (size_t)(g + r) * HV4;
      ra[r] = __builtin_nontemporal_load(rp + lane);
      rb[r] = __builtin_nontemporal_load(rp + lane + 64);
      rc[r] = __builtin_nontemporal_load(rp + lane + 128);
    }

    float pd[RGROUP];
    #pragma unroll
    for (int r = 0; r < RGROUP; ++r)
      pd[r] = dot4(ra[r], qa) + dot4(rb[r], qb) + dot4(rc[r], qc);

    // interleaved 64-lane butterfly sums -> scores wave-uniform afterwards
    #pragma unroll
    for (int off = 32; off >= 1; off >>= 1) {
      #pragma unroll
      for (int r = 0; r < RGROUP; ++r)
        pd[r] += __shfl_xor(pd[r], off, 64);
    }

    const float gm = fmaxf(pd[0], pd[1]);
    if (gm > m) {                       // wave-uniform branch
      const float a = __expf(m - gm);   // exp(-inf)=0 on first group
      l *= a;
      oa *= a; ob *= a; oc *= a;
      m = gm;
    }

    #pragma unroll
    for (int r = 0; r < RGROUP; ++r) {
      const float p = __expf(pd[r] - m);
      l += p;
      oa += p * ra[r];
      ob += p * rb[r];
      oc += p * rc[r];
    }
  }

  // Combine the 4 wave partials in LDS
  __shared__ float s_o[NWAVES][HID];   // 12 KB
  __shared__ float s_m[NWAVES];
  __shared__ float s_l[NWAVES];
  f4v* so4 = reinterpret_cast<f4v*>(s_o[wave]);
  so4[lane]       = oa;
  so4[lane + 64]  = ob;
  so4[lane + 128] = oc;
  if (lane == 0) { s_m[wave] = m; s_l[wave] = l; }
  __syncthreads();

  const float mb = fmaxf(fmaxf(s_m[0], s_m[1]), fmaxf(s_m[2], s_m[3]));
  const float a0 = __expf(s_m[0] - mb);
  const float a1 = __expf(s_m[1] - mb);
  const float a2 = __expf(s_m[2] - mb);
  const float a3 = __expf(s_m[3] - mb);
  const float lb = a0 * s_l[0] + a1 * s_l[1] + a2 * s_l[2] + a3 * s_l[3];

  const int pidx = b * CHUNKS + chunk;
  float* O = o_ws + (size_t)pidx * HID;
  #pragma unroll
  for (int j = 0; j < 3; ++j) {
    const int h = tid + 256 * j;
    O[h] = a0 * s_o[0][h] + a1 * s_o[1][h] + a2 * s_o[2][h] + a3 * s_o[3][h];
  }
  if (tid == 0) { m_ws[pidx] = mb; l_ws[pidx] = lb; }
}

// Pass 2: one thread per output element. grid (BATCH, 6) x 128 threads.
// m/l loads are redundant per thread but fully L2-resident (8 KB total).
__global__ __launch_bounds__(128)
void attn_pass2(const float* __restrict__ m_ws,
                const float* __restrict__ l_ws,
                const float* __restrict__ o_ws,
                float* __restrict__ out) {
  const int b = blockIdx.x;
  const int h = blockIdx.y * 128 + threadIdx.x;

  float mg = -INFINITY;
  #pragma unroll 8
  for (int c = 0; c < CHUNKS; ++c)
    mg = fmaxf(mg, m_ws[b * CHUNKS + c]);

  float L = 0.0f;
  float acc = 0.0f;
  #pragma unroll 8
  for (int c = 0; c < CHUNKS; ++c) {
    const int pi = b * CHUNKS + c;
    const float a = __expf(m_ws[pi] - mg);
    L += a * l_ws[pi];
    acc += a * o_ws[(size_t)pi * HID + h];
  }
  out[(size_t)b * HID + h] = acc / L;
}

extern "C" void kernel_launch(void* const* d_in, const int* in_sizes, int n_in,
                              void* d_out, int out_size, void* d_ws, size_t ws_size,
                              hipStream_t stream) {
  const float* hidden = (const float*)d_in[0];   // [32, 4096, 768] fp32
  const float* q      = (const float*)d_in[1];   // [1, 768] fp32
  float* out = (float*)d_out;                    // [32, 768] fp32

  // Workspace layout: m[2048] | l[2048] | O[2048*768]  (~6.3 MB total)
  float* m_ws = (float*)d_ws;
  float* l_ws = m_ws + BATCH * CHUNKS;
  float* o_ws = l_ws + BATCH * CHUNKS;

  dim3 grid1(CHUNKS, BATCH);
  attn_pass1<<<grid1, 256, 0, stream>>>(hidden, q, m_ws, l_ws, o_ws);
  dim3 grid2(BATCH, HID / 128);
  attn_pass2<<<grid2, 128, 0, stream>>>(m_ws, l_ws, o_ws, out);
}